// Round 7
// baseline (358.064 us; speedup 1.0000x reference)
//
#include <hip/hip_runtime.h>
#include <hip/hip_bf16.h>

// FRMIL: B=8, N=4096, D=1024, H=8 (dh=128), NC=2, image 64x64.
// Single-query attention: K/V GEMMs never materialized.
// NOTE: qh·bk_h is constant across keys -> cancels in softmax -> dropped.
// R1: split k_fused into k_logits/k_sm/k_yacc for occupancy.
// R2: launch_bounds (512,6)->(512,4): 40-VGPR spills (306MB/dispatch scratch).
// R3: conv once; xf materialized; k_ysum streaming weighted sum.
// R6: chunk 128->64, k_sm fused into k_ysum. 344us; all kernels < fill (78us).
// R7: k_logits still ~2.5x its VALU floor (latency/barrier-bound at 4 blocks/CU,
//     wave-capped). Blocks halved again: 256 thr, 32-ch chunks, grid 16384,
//     LDS 16KB union -> 8 blocks/CU (full 32-wave cap). Per-thread work
//     identical; only partitioning changes. plog -> 32 chunks (32MB).

#define NTOK 4096
#define DD 1024

// ---------------- ws float offsets ----------------
#define FO_ARG 0         // 8 u64 = 16 floats
#define FO_S1  16        // 2048 u64 = 4096 floats
#define FO_CWT 4160      // 9216
#define FO_QP  13376     // 8192
#define FO_W   21568     // 65536
#define FO_MS  87232     // 64bh * 64tile * 2 = 8192
#define FO_YP  95424     // 64bh * 64tile * 1024 = 4194304
#define FO_Y   4289728   // 65536
#define FO_O1  4355264   // 8192
#define FO_O2  4363456   // 8192
#define FO_XF  8388608   // xf: 8b*64tile*64tok*1024ch = 32M floats (128MB)
#define FO_PL  41943040  // plog: 16384 blocks * 512 = 8M floats (32MB)

#define LSTRIDE 101      // float4 stride per ch-group in staging LDS

__global__ void k_init(const float* __restrict__ convw, float* __restrict__ cwT) {
  int gid = blockIdx.x * 256 + threadIdx.x;
  if (gid < 9216) {
    int d = gid / 9, p = gid - d * 9;
    cwT[p * DD + d] = convw[gid];
  }
}

// ---------- argmax: stage 1 (no atomics), stage 2 ----------
__global__ void k_argmax1(const float* __restrict__ inp, const float* __restrict__ Wenc,
                          const float* __restrict__ benc, unsigned long long* __restrict__ s1buf) {
  __shared__ unsigned long long lb[4];
  int wave = threadIdx.x >> 6, lane = threadIdx.x & 63;
  int b = blockIdx.x >> 8;
  int r0 = ((blockIdx.x & 255) << 4) + (wave << 2);
  const float4* base = (const float4*)(inp + ((size_t)b * NTOK + r0) * DD);
  const float4* wp = (const float4*)Wenc;
  float s0 = 0.f, s1 = 0.f, s2 = 0.f, s3 = 0.f;
#pragma unroll
  for (int k = 0; k < 4; ++k) {
    int off = lane + (k << 6);
    float4 w4 = wp[off];
    float4 a0 = base[off];
    float4 a1 = base[256 + off];
    float4 a2 = base[512 + off];
    float4 a3 = base[768 + off];
    s0 = fmaf(w4.x, a0.x, s0); s0 = fmaf(w4.y, a0.y, s0); s0 = fmaf(w4.z, a0.z, s0); s0 = fmaf(w4.w, a0.w, s0);
    s1 = fmaf(w4.x, a1.x, s1); s1 = fmaf(w4.y, a1.y, s1); s1 = fmaf(w4.z, a1.z, s1); s1 = fmaf(w4.w, a1.w, s1);
    s2 = fmaf(w4.x, a2.x, s2); s2 = fmaf(w4.y, a2.y, s2); s2 = fmaf(w4.z, a2.z, s2); s2 = fmaf(w4.w, a2.w, s2);
    s3 = fmaf(w4.x, a3.x, s3); s3 = fmaf(w4.y, a3.y, s3); s3 = fmaf(w4.z, a3.z, s3); s3 = fmaf(w4.w, a3.w, s3);
  }
#pragma unroll
  for (int mk = 32; mk >= 1; mk >>= 1) {
    s0 += __shfl_xor(s0, mk); s1 += __shfl_xor(s1, mk);
    s2 += __shfl_xor(s2, mk); s3 += __shfl_xor(s3, mk);
  }
  if (lane == 0) {
    float be = benc[0];
    float v[4] = {s0 + be, s1 + be, s2 + be, s3 + be};
    unsigned long long bst = 0ull;
#pragma unroll
    for (int i = 0; i < 4; ++i) {
      unsigned u = __float_as_uint(v[i]);
      u = (u & 0x80000000u) ? ~u : (u | 0x80000000u);
      unsigned long long p = ((unsigned long long)u << 32) |
                             (unsigned long long)(0xFFFFFFFFu - (unsigned)(r0 + i));
      bst = bst > p ? bst : p;
    }
    lb[wave] = bst;
  }
  __syncthreads();
  if (threadIdx.x == 0) {
    unsigned long long m = lb[0];
#pragma unroll
    for (int i = 1; i < 4; ++i) m = m > lb[i] ? m : lb[i];
    s1buf[blockIdx.x] = m;
  }
}

__global__ void k_argmax2(const unsigned long long* __restrict__ s1buf,
                          unsigned long long* __restrict__ argbest) {
  __shared__ unsigned long long red[256];
  int tid = threadIdx.x, b = blockIdx.x;
  red[tid] = s1buf[b * 256 + tid];
  __syncthreads();
  for (int s = 128; s > 0; s >>= 1) {
    if (tid < s) { unsigned long long o = red[tid + s]; if (o > red[tid]) red[tid] = o; }
    __syncthreads();
  }
  if (tid == 0) argbest[b] = red[0];
}

__global__ void k_qp(const float* __restrict__ inp, const float* __restrict__ Wq,
                     const float* __restrict__ bq, const unsigned long long* __restrict__ argbest,
                     float* __restrict__ Qp) {
  int wave = threadIdx.x >> 6, lane = threadIdx.x & 63;
  int b = blockIdx.x >> 8;
  int i = ((blockIdx.x & 255) << 2) + wave;
  unsigned idx = 0xFFFFFFFFu - (unsigned)(argbest[b] & 0xFFFFFFFFull);
  const float4* qr = (const float4*)(inp + ((size_t)b * NTOK + idx) * DD);
  const float4* wr = (const float4*)(Wq + (size_t)i * DD);
  float s = 0.f;
#pragma unroll
  for (int k = 0; k < 4; ++k) {
    float4 a = wr[lane + (k << 6)], x = qr[lane + (k << 6)];
    s = fmaf(a.x, x.x, s); s = fmaf(a.y, x.y, s);
    s = fmaf(a.z, x.z, s); s = fmaf(a.w, x.w, s);
  }
  for (int m = 32; m > 0; m >>= 1) s += __shfl_xor(s, m);
  if (lane == 0) Qp[b * DD + i] = s + bq[i];
}

// ---------- w[b,h,:] = Wk_h^T · Qp_h : Wk read ONCE, reused across 8 batches ----------
__global__ void k_w(const float* __restrict__ Wk, const float* __restrict__ Qp,
                    float* __restrict__ wbuf) {
  __shared__ float qs[1024];   // [b][i] for this head
  __shared__ float sred[2048]; // [ig][b][jl]
  const int tid = threadIdx.x;
  const int h = blockIdx.x >> 5, jb = blockIdx.x & 31;
  {
    int b = tid >> 5, i4 = tid & 31;
    ((float4*)qs)[b * 32 + i4] = ((const float4*)Qp)[b * 256 + (h << 5) + i4];
  }
  __syncthreads();
  const int jl = tid & 31, ig = tid >> 5;
  const float* wkp = Wk + (size_t)((h << 7) + (ig << 4)) * DD + (jb << 5) + jl;
  float acc[8];
#pragma unroll
  for (int b = 0; b < 8; ++b) acc[b] = 0.f;
#pragma unroll
  for (int ii = 0; ii < 16; ++ii) {
    float wv = wkp[(size_t)ii * DD];
    int i = (ig << 4) + ii;
#pragma unroll
    for (int b = 0; b < 8; ++b) acc[b] = fmaf(qs[(b << 7) + i], wv, acc[b]);
  }
#pragma unroll
  for (int b = 0; b < 8; ++b) sred[ig * 256 + (b << 5) + jl] = acc[b];
  __syncthreads();
  {
    int b = tid >> 5, j2 = tid & 31;
    float s = 0.f;
#pragma unroll
    for (int g = 0; g < 8; ++g) s += sred[g * 256 + (b << 5) + j2];
    wbuf[(size_t)((b << 3) + h) * DD + (jb << 5) + j2] = s;
  }
}

// ---------- logits + xf store: grid 16384 = b(8) x tile(64) x chunk(32), 256 thr ----------
// 32 ch per chunk; LDS 16KB union (staging 8x101 f4 / reduce 4096 f / transpose 64x9 f4).
// 256 thr = 4 waves -> 8 blocks/CU (full 32-wave cap). Per-thread work identical to R6.
__global__ __launch_bounds__(256, 8) void k_logits(
    const float* __restrict__ inp, const float* __restrict__ convb,
    const float* __restrict__ cwT, const float* __restrict__ wbuf,
    const unsigned long long* __restrict__ argbest,
    float* __restrict__ plog, float* __restrict__ xf) {
  __shared__ float4 sred4[1024];   // 16 KB
  const int tid = threadIdx.x, bx = blockIdx.x;
  const int b = bx >> 11, tile = (bx >> 5) & 63, cidx = bx & 31;
  const int R0 = (tile >> 3) << 3, C0 = (tile & 7) << 3;
  const unsigned idxq = 0xFFFFFFFFu - (unsigned)(argbest[b] & 0xFFFFFFFFull);
  const float* inpb = inp + (size_t)b * NTOK * DD;
  const float* qrow = inpb + (size_t)idxq * DD;
  const int gg = tid & 7, ts = tid >> 3;                       // staging roles
  const int jg = tid >> 5, rq = (tid >> 3) & 3, ca = tid & 7;  // conv roles
  const int r0a = rq << 1;
  const int jc = cidx << 5;

  float acc[2][8];
#pragma unroll
  for (int i = 0; i < 2; ++i)
#pragma unroll
    for (int h = 0; h < 8; ++h) acc[i][h] = 0.f;
  float4 xs0, xs1;   // conv features kept for xf store

  {  // stage 32 channels of the 10x10 halo (relu(x - q))
    const int js = jc + (gg << 2);
    float4 qv = *(const float4*)(qrow + js);
    for (int t = ts; t < 100; t += 32) {
      int tr = t / 10, tc = t - tr * 10;
      int gr = R0 - 1 + tr, gc = C0 - 1 + tc;
      float4 v = make_float4(0.f, 0.f, 0.f, 0.f);
      if (gr >= 0 && gr < 64 && gc >= 0 && gc < 64) {
        float4 rv = *(const float4*)(inpb + (size_t)((gr << 6) + gc) * DD + js);
        v.x = fmaxf(rv.x - qv.x, 0.f); v.y = fmaxf(rv.y - qv.y, 0.f);
        v.z = fmaxf(rv.z - qv.z, 0.f); v.w = fmaxf(rv.w - qv.w, 0.f);
      }
      sred4[gg * LSTRIDE + t] = v;
    }
  }
  __syncthreads();
  {
    const int j4 = jc + (jg << 2);
    float4 cwr[9];
#pragma unroll
    for (int p = 0; p < 9; ++p) cwr[p] = *(const float4*)(cwT + p * DD + j4);
    float4 cb4 = *(const float4*)(convb + j4);
    const float4* fb = sred4 + jg * LSTRIDE;
    float4 x0 = cb4, x1 = cb4;
    {
      float4 rw[4][3];
#pragma unroll
      for (int rr = 0; rr < 4; ++rr)
#pragma unroll
        for (int dc = 0; dc < 3; ++dc)
          rw[rr][dc] = fb[(r0a + rr) * 10 + ca + dc];
#pragma unroll
      for (int dr = 0; dr < 3; ++dr)
#pragma unroll
        for (int dc = 0; dc < 3; ++dc) {
          float4 w = cwr[dr * 3 + dc];
          float4 f0 = rw[dr][dc], f1 = rw[dr + 1][dc];
          x0.x = fmaf(w.x, f0.x, x0.x); x0.y = fmaf(w.y, f0.y, x0.y);
          x0.z = fmaf(w.z, f0.z, x0.z); x0.w = fmaf(w.w, f0.w, x0.w);
          x1.x = fmaf(w.x, f1.x, x1.x); x1.y = fmaf(w.y, f1.y, x1.y);
          x1.z = fmaf(w.z, f1.z, x1.z); x1.w = fmaf(w.w, f1.w, x1.w);
        }
      x0.x += rw[1][1].x; x0.y += rw[1][1].y; x0.z += rw[1][1].z; x0.w += rw[1][1].w;
      x1.x += rw[2][1].x; x1.y += rw[2][1].y; x1.z += rw[2][1].z; x1.w += rw[2][1].w;
    }
    xs0 = x0; xs1 = x1;
#pragma unroll
    for (int h = 0; h < 8; ++h) {
      float4 whv = *(const float4*)(wbuf + (size_t)(b * 8 + h) * DD + j4);
      float a0 = acc[0][h], a1 = acc[1][h];
      a0 = fmaf(whv.x, x0.x, a0); a0 = fmaf(whv.y, x0.y, a0);
      a0 = fmaf(whv.z, x0.z, a0); a0 = fmaf(whv.w, x0.w, a0);
      a1 = fmaf(whv.x, x1.x, a1); a1 = fmaf(whv.y, x1.y, a1);
      a1 = fmaf(whv.z, x1.z, a1); a1 = fmaf(whv.w, x1.w, a1);
      acc[0][h] = a0; acc[1][h] = a1;
    }
  }
  // ---- reduce over 8 ch-groups -> per-chunk partial logits ----
  __syncthreads();
  float* red = (float*)sred4;
#pragma unroll
  for (int it = 0; it < 2; ++it)
#pragma unroll
    for (int h = 0; h < 8; ++h)
      red[jg * 512 + ((r0a + it) * 8 + ca) * 8 + h] = acc[it][h];
  __syncthreads();
  {
#pragma unroll
    for (int half = 0; half < 2; ++half) {
      int o = (half << 8) + tid;
      float s = 0.f;
#pragma unroll
      for (int g = 0; g < 8; ++g) s += red[g * 512 + o];
      plog[(size_t)bx * 512 + o] = s;
    }
  }
  // ---- xf store: transpose regs -> LDS -> coalesced global ----
  __syncthreads();   // all red reads complete before overwrite
  float4* ldsx = sred4;  // [64 tok][9 float4] (pad 1)
  {
    const int tk0 = (r0a << 3) + ca;
    ldsx[tk0 * 9 + jg] = xs0;
    ldsx[(tk0 + 8) * 9 + jg] = xs1;
  }
  __syncthreads();
  {
    float* xfb = xf + (size_t)((b << 6) + tile) * (64 * DD) + jc;
#pragma unroll
    for (int it = 0; it < 2; ++it) {
      int idx = (it << 8) + tid;       // 0..511
      int tk = idx >> 3, q = idx & 7;
      float4 v = ldsx[tk * 9 + q];
      *(float4*)(xfb + (size_t)tk * DD + (q << 2)) = v;
    }
  }
}

// ---------- y pass (softmax fused): grid 512 = b x tile, 512 thr ----------
__global__ __launch_bounds__(512, 8) void k_ysum(
    const float* __restrict__ plog, const float* __restrict__ xf,
    float2* __restrict__ msbuf, float* __restrict__ ypart) {
  __shared__ float atile[512];
  const int tid = threadIdx.x, bt = blockIdx.x;
  // ---- sum 32 chunk-partials; logit at [tok*8+h] ----
  {
    const float* pp = plog + ((size_t)bt << 5) * 512;
    float s = 0.f;
#pragma unroll
    for (int c = 0; c < 32; ++c) s += pp[c * 512 + tid];
    atile[tid] = s * 0.03125f;
  }
  __syncthreads();
  // ---- per-head softmax: wave w = head, lane l = token ----
  {
    const int w = tid >> 6, l = tid & 63;
    float v = atile[l * 8 + w];
    float mx = v;
#pragma unroll
    for (int mk = 32; mk >= 1; mk >>= 1) mx = fmaxf(mx, __shfl_xor(mx, mk));
    float e = __expf(v - mx);
    float Ss = e;
#pragma unroll
    for (int mk = 32; mk >= 1; mk >>= 1) Ss += __shfl_xor(Ss, mk);
    __syncthreads();   // all reads of atile done before overwrite
    atile[l * 8 + w] = e;
    if (l == 0) {
      int b = bt >> 6, tile = bt & 63;
      msbuf[((b << 3) + w) * 64 + tile] = make_float2(mx, Ss);
    }
  }
  __syncthreads();
  // ---- streaming weighted sum over xf ----
  const float* xbase = xf + (size_t)bt * (64 * DD) + (tid << 1);
  float2 acc[8];
#pragma unroll
  for (int h = 0; h < 8; ++h) acc[h] = make_float2(0.f, 0.f);
#pragma unroll 4
  for (int t = 0; t < 64; ++t) {
    float2 v = *(const float2*)(xbase + (size_t)t * DD);
    float4 aA = *(const float4*)&atile[t * 8];
    float4 aB = *(const float4*)&atile[t * 8 + 4];
    acc[0].x = fmaf(aA.x, v.x, acc[0].x); acc[0].y = fmaf(aA.x, v.y, acc[0].y);
    acc[1].x = fmaf(aA.y, v.x, acc[1].x); acc[1].y = fmaf(aA.y, v.y, acc[1].y);
    acc[2].x = fmaf(aA.z, v.x, acc[2].x); acc[2].y = fmaf(aA.z, v.y, acc[2].y);
    acc[3].x = fmaf(aA.w, v.x, acc[3].x); acc[3].y = fmaf(aA.w, v.y, acc[3].y);
    acc[4].x = fmaf(aB.x, v.x, acc[4].x); acc[4].y = fmaf(aB.x, v.y, acc[4].y);
    acc[5].x = fmaf(aB.y, v.x, acc[5].x); acc[5].y = fmaf(aB.y, v.y, acc[5].y);
    acc[6].x = fmaf(aB.z, v.x, acc[6].x); acc[6].y = fmaf(aB.z, v.y, acc[6].y);
    acc[7].x = fmaf(aB.w, v.x, acc[7].x); acc[7].y = fmaf(aB.w, v.y, acc[7].y);
  }
  const int b = bt >> 6, tile = bt & 63;
#pragma unroll
  for (int h = 0; h < 8; ++h)
    *(float2*)(ypart + ((size_t)((b * 8 + h) * 64 + tile)) * DD + (tid << 1)) = acc[h];
}

// ---------- flash-combine (512 blocks: bh x 8 ch-splits); computes l0 inline ----------
__global__ void k_comb(const float2* __restrict__ msbuf, const float* __restrict__ wbuf,
                       const float* __restrict__ cls, const float* __restrict__ ypart,
                       float* __restrict__ ybuf) {
  __shared__ float redl[256];
  __shared__ float wgt[64];
  __shared__ float wclss;
  __shared__ float4 sacc[256];
  int tid = threadIdx.x;
  int bh = blockIdx.x >> 3, cs = blockIdx.x & 7;
  {  // l0 = (w . cls) * scale   (qh·bk_h dropped: softmax-invariant)
    float4 a = ((const float4*)(wbuf + (size_t)bh * DD))[tid];
    float4 c = ((const float4*)cls)[tid];
    redl[tid] = a.x * c.x + a.y * c.y + a.z * c.z + a.w * c.w;
  }
  __syncthreads();
  for (int s = 128; s > 0; s >>= 1) { if (tid < s) redl[tid] += redl[tid + s]; __syncthreads(); }
  float l0 = redl[0] * 0.03125f;
  if (tid < 64) {
    float2 ms = msbuf[bh * 64 + tid];
    float m = ms.x, S = ms.y;
    float M = m;
#pragma unroll
    for (int mk = 32; mk >= 1; mk >>= 1) M = fmaxf(M, __shfl_xor(M, mk));
    M = fmaxf(M, l0);
    float w = __expf(m - M);
    float z = S * w;
#pragma unroll
    for (int mk = 32; mk >= 1; mk >>= 1) z += __shfl_xor(z, mk);
    float ec = __expf(l0 - M);
    float Z = z + ec;
    wgt[tid] = w / Z;
    if (tid == 0) wclss = ec / Z;
  }
  __syncthreads();
  int ch4 = (cs << 5) + (tid & 31);
  int tg = tid >> 5;
  const float* yp = ypart + (size_t)bh * 64 * DD + (ch4 << 2);
  float4 acc = make_float4(0.f, 0.f, 0.f, 0.f);
#pragma unroll
  for (int tt = 0; tt < 8; ++tt) {
    int t = tg * 8 + tt;
    float w = wgt[t];
    float4 v = *(const float4*)(yp + (size_t)t * DD);
    acc.x = fmaf(w, v.x, acc.x); acc.y = fmaf(w, v.y, acc.y);
    acc.z = fmaf(w, v.z, acc.z); acc.w = fmaf(w, v.w, acc.w);
  }
  sacc[tg * 32 + (tid & 31)] = acc;
  __syncthreads();
  if (tid < 32) {
    int c4 = (cs << 5) + tid;
    float4 s = sacc[tid];
#pragma unroll
    for (int g = 1; g < 8; ++g) {
      float4 v = sacc[g * 32 + tid];
      s.x += v.x; s.y += v.y; s.z += v.z; s.w += v.w;
    }
    float wc = wclss;
    float4 cv = *(const float4*)(cls + (c4 << 2));
    s.x = fmaf(wc, cv.x, s.x); s.y = fmaf(wc, cv.y, s.y);
    s.z = fmaf(wc, cv.z, s.z); s.w = fmaf(wc, cv.w, s.w);
    *(float4*)(ybuf + (size_t)bh * DD + (c4 << 2)) = s;
  }
}

__global__ void k_o1(const float* __restrict__ Wv, const float* __restrict__ bv,
                     const float* __restrict__ Qp, const float* __restrict__ ybuf,
                     float* __restrict__ O1) {
  int wave = threadIdx.x >> 6, lane = threadIdx.x & 63;
  int b = blockIdx.x >> 8;
  int i = ((blockIdx.x & 255) << 2) + wave;
  int h = i >> 7;
  const float4* wr = (const float4*)(Wv + (size_t)i * DD);
  const float4* yr = (const float4*)(ybuf + (size_t)(b * 8 + h) * DD);
  float s = 0.f;
#pragma unroll
  for (int k = 0; k < 4; ++k) {
    float4 a = wr[lane + (k << 6)], x = yr[lane + (k << 6)];
    s = fmaf(a.x, x.x, s); s = fmaf(a.y, x.y, s);
    s = fmaf(a.z, x.z, s); s = fmaf(a.w, x.w, s);
  }
  for (int m = 32; m > 0; m >>= 1) s += __shfl_xor(s, m);
  if (lane == 0) O1[b * DD + i] = Qp[b * DD + i] + bv[i] + s;
}

__global__ void k_o2(const float* __restrict__ Wo, const float* __restrict__ bo,
                     const float* __restrict__ O1, float* __restrict__ O2) {
  int wave = threadIdx.x >> 6, lane = threadIdx.x & 63;
  int b = blockIdx.x >> 8;
  int i = ((blockIdx.x & 255) << 2) + wave;
  const float4* wr = (const float4*)(Wo + (size_t)i * DD);
  const float4* xr = (const float4*)(O1 + (size_t)b * DD);
  float s = 0.f;
#pragma unroll
  for (int k = 0; k < 4; ++k) {
    float4 a = wr[lane + (k << 6)], x = xr[lane + (k << 6)];
    s = fmaf(a.x, x.x, s); s = fmaf(a.y, x.y, s);
    s = fmaf(a.z, x.z, s); s = fmaf(a.w, x.w, s);
  }
  for (int m = 32; m > 0; m >>= 1) s += __shfl_xor(s, m);
  if (lane == 0) O2[b * DD + i] = O1[b * DD + i] + fmaxf(s + bo[i], 0.f);
}

__global__ void k_out(const float* __restrict__ Wfc, const float* __restrict__ bfc,
                      const float* __restrict__ O2, float* __restrict__ out) {
  int wave = threadIdx.x >> 6, lane = threadIdx.x & 63;
  for (int p = wave; p < 16; p += 4) {
    int b = p >> 1, cc = p & 1;
    const float4* o = (const float4*)(O2 + (size_t)b * DD);
    const float4* wr = (const float4*)(Wfc + (size_t)cc * DD);
    float s = 0.f;
#pragma unroll
    for (int k = 0; k < 4; ++k) {
      float4 a = o[lane + (k << 6)], x = wr[lane + (k << 6)];
      s = fmaf(a.x, x.x, s); s = fmaf(a.y, x.y, s);
      s = fmaf(a.z, x.z, s); s = fmaf(a.w, x.w, s);
    }
    for (int m = 32; m > 0; m >>= 1) s += __shfl_xor(s, m);
    if (lane == 0) out[p] = s + bfc[cc];
  }
}

extern "C" void kernel_launch(void* const* d_in, const int* in_sizes, int n_in,
                              void* d_out, int out_size, void* d_ws, size_t ws_size,
                              hipStream_t stream) {
  const float* inp   = (const float*)d_in[0];
  const float* Wenc  = (const float*)d_in[1];
  const float* benc  = (const float*)d_in[2];
  const float* cls   = (const float*)d_in[3];
  const float* convw = (const float*)d_in[4];
  const float* convb = (const float*)d_in[5];
  const float* Wq    = (const float*)d_in[6];
  const float* bq    = (const float*)d_in[7];
  const float* Wk    = (const float*)d_in[8];
  const float* bv    = (const float*)d_in[11];
  const float* Wv    = (const float*)d_in[10];
  const float* Wo    = (const float*)d_in[12];
  const float* bo    = (const float*)d_in[13];
  const float* Wfc   = (const float*)d_in[14];
  const float* bfc   = (const float*)d_in[15];
  float* out = (float*)d_out;
  float* W = (float*)d_ws;
  unsigned long long* argbest = (unsigned long long*)(W + FO_ARG);
  unsigned long long* s1buf   = (unsigned long long*)(W + FO_S1);
  float* cwT   = W + FO_CWT;
  float* Qp    = W + FO_QP;
  float* wbuf  = W + FO_W;
  float2* msbuf = (float2*)(W + FO_MS);
  float* ypart = W + FO_YP;
  float* plog  = W + FO_PL;
  float* xf    = W + FO_XF;
  float* ybuf  = W + FO_Y;
  float* O1    = W + FO_O1;
  float* O2    = W + FO_O2;

  hipLaunchKernelGGL(k_init,    dim3(36),    dim3(256), 0, stream, convw, cwT);
  hipLaunchKernelGGL(k_argmax1, dim3(2048),  dim3(256), 0, stream, inp, Wenc, benc, s1buf);
  hipLaunchKernelGGL(k_argmax2, dim3(8),     dim3(256), 0, stream, s1buf, argbest);
  hipLaunchKernelGGL(k_qp,      dim3(2048),  dim3(256), 0, stream, inp, Wq, bq, argbest, Qp);
  hipLaunchKernelGGL(k_w,       dim3(256),   dim3(256), 0, stream, Wk, Qp, wbuf);
  hipLaunchKernelGGL(k_logits,  dim3(16384), dim3(256), 0, stream, inp, convb, cwT, wbuf, argbest, plog, xf);
  hipLaunchKernelGGL(k_ysum,    dim3(512),   dim3(512), 0, stream, plog, xf, msbuf, ypart);
  hipLaunchKernelGGL(k_comb,    dim3(512),   dim3(256), 0, stream, msbuf, wbuf, cls, ypart, ybuf);
  hipLaunchKernelGGL(k_o1,      dim3(2048),  dim3(256), 0, stream, Wv, bv, Qp, ybuf, O1);
  hipLaunchKernelGGL(k_o2,      dim3(2048),  dim3(256), 0, stream, Wo, bo, O1, O2);
  hipLaunchKernelGGL(k_out,     dim3(1),     dim3(256), 0, stream, Wfc, bfc, O2, out);
}

// Round 9
// 339.818 us; speedup vs baseline: 1.0537x; 1.0537x over previous
//
#include <hip/hip_runtime.h>
#include <hip/hip_bf16.h>

// FRMIL: B=8, N=4096, D=1024, H=8 (dh=128), NC=2, image 64x64.
// Single-query attention: K/V GEMMs never materialized.
// R1: split k_fused for occupancy. R2: fix VGPR spills. R3: conv once (xf spill).
// R6: 64-ch chunks, grid 8192, 32KB LDS, k_sm fused into k_ysum -> 344us (best).
// R7 FAILED: 32-ch chunks -> write-granule splitting + 2x per-block overhead;
//     occupancy lever exhausted at 4 blocks/CU.
// R8: revert to R6 structure; k_argmax2 eliminated via device-scope atomicMax
//     (argbest zero-init in k_init; packed keys always > 0 so 0 is identity).
// R9: resubmit after infra failure; fixed s3 fma z/w order (bit-identical argmax).

#define NTOK 4096
#define DD 1024

// ---------------- ws float offsets ----------------
#define FO_ARG 0         // 8 u64 = 16 floats
#define FO_CWT 4160      // 9216
#define FO_QP  13376     // 8192
#define FO_W   21568     // 65536
#define FO_MS  87232     // 64bh * 64tile * 2 = 8192
#define FO_YP  95424     // 64bh * 64tile * 1024 = 4194304
#define FO_Y   4289728   // 65536
#define FO_O1  4355264   // 8192
#define FO_O2  4363456   // 8192
#define FO_XF  8388608   // xf: 8b*64tile*64tok*1024ch = 32M floats (128MB)
#define FO_PL  41943040  // plog: 8192 blocks * 512 = 4M floats (16MB)

#define LSTRIDE 101      // float4 stride per ch-group in staging LDS

__global__ void k_init(const float* __restrict__ convw, float* __restrict__ cwT,
                       unsigned long long* __restrict__ argbest) {
  int gid = blockIdx.x * 256 + threadIdx.x;
  if (gid < 8) argbest[gid] = 0ull;
  if (gid < 9216) {
    int d = gid / 9, p = gid - d * 9;
    cwT[p * DD + d] = convw[gid];
  }
}

// ---------- argmax: per-block best -> device-scope atomicMax ----------
__global__ void k_argmax1(const float* __restrict__ inp, const float* __restrict__ Wenc,
                          const float* __restrict__ benc, unsigned long long* __restrict__ argbest) {
  __shared__ unsigned long long lb[4];
  int wave = threadIdx.x >> 6, lane = threadIdx.x & 63;
  int b = blockIdx.x >> 8;
  int r0 = ((blockIdx.x & 255) << 4) + (wave << 2);
  const float4* base = (const float4*)(inp + ((size_t)b * NTOK + r0) * DD);
  const float4* wp = (const float4*)Wenc;
  float s0 = 0.f, s1 = 0.f, s2 = 0.f, s3 = 0.f;
#pragma unroll
  for (int k = 0; k < 4; ++k) {
    int off = lane + (k << 6);
    float4 w4 = wp[off];
    float4 a0 = base[off];
    float4 a1 = base[256 + off];
    float4 a2 = base[512 + off];
    float4 a3 = base[768 + off];
    s0 = fmaf(w4.x, a0.x, s0); s0 = fmaf(w4.y, a0.y, s0); s0 = fmaf(w4.z, a0.z, s0); s0 = fmaf(w4.w, a0.w, s0);
    s1 = fmaf(w4.x, a1.x, s1); s1 = fmaf(w4.y, a1.y, s1); s1 = fmaf(w4.z, a1.z, s1); s1 = fmaf(w4.w, a1.w, s1);
    s2 = fmaf(w4.x, a2.x, s2); s2 = fmaf(w4.y, a2.y, s2); s2 = fmaf(w4.z, a2.z, s2); s2 = fmaf(w4.w, a2.w, s2);
    s3 = fmaf(w4.x, a3.x, s3); s3 = fmaf(w4.y, a3.y, s3); s3 = fmaf(w4.z, a3.z, s3); s3 = fmaf(w4.w, a3.w, s3);
  }
#pragma unroll
  for (int mk = 32; mk >= 1; mk >>= 1) {
    s0 += __shfl_xor(s0, mk); s1 += __shfl_xor(s1, mk);
    s2 += __shfl_xor(s2, mk); s3 += __shfl_xor(s3, mk);
  }
  if (lane == 0) {
    float be = benc[0];
    float v[4] = {s0 + be, s1 + be, s2 + be, s3 + be};
    unsigned long long bst = 0ull;
#pragma unroll
    for (int i = 0; i < 4; ++i) {
      unsigned u = __float_as_uint(v[i]);
      u = (u & 0x80000000u) ? ~u : (u | 0x80000000u);
      unsigned long long p = ((unsigned long long)u << 32) |
                             (unsigned long long)(0xFFFFFFFFu - (unsigned)(r0 + i));
      bst = bst > p ? bst : p;
    }
    lb[wave] = bst;
  }
  __syncthreads();
  if (threadIdx.x == 0) {
    unsigned long long m = lb[0];
#pragma unroll
    for (int i = 1; i < 4; ++i) m = m > lb[i] ? m : lb[i];
    atomicMax(&argbest[b], m);
  }
}

__global__ void k_qp(const float* __restrict__ inp, const float* __restrict__ Wq,
                     const float* __restrict__ bq, const unsigned long long* __restrict__ argbest,
                     float* __restrict__ Qp) {
  int wave = threadIdx.x >> 6, lane = threadIdx.x & 63;
  int b = blockIdx.x >> 8;
  int i = ((blockIdx.x & 255) << 2) + wave;
  unsigned idx = 0xFFFFFFFFu - (unsigned)(argbest[b] & 0xFFFFFFFFull);
  const float4* qr = (const float4*)(inp + ((size_t)b * NTOK + idx) * DD);
  const float4* wr = (const float4*)(Wq + (size_t)i * DD);
  float s = 0.f;
#pragma unroll
  for (int k = 0; k < 4; ++k) {
    float4 a = wr[lane + (k << 6)], x = qr[lane + (k << 6)];
    s = fmaf(a.x, x.x, s); s = fmaf(a.y, x.y, s);
    s = fmaf(a.z, x.z, s); s = fmaf(a.w, x.w, s);
  }
  for (int m = 32; m > 0; m >>= 1) s += __shfl_xor(s, m);
  if (lane == 0) Qp[b * DD + i] = s + bq[i];
}

// ---------- w[b,h,:] = Wk_h^T · Qp_h : Wk read ONCE, reused across 8 batches ----------
__global__ void k_w(const float* __restrict__ Wk, const float* __restrict__ Qp,
                    float* __restrict__ wbuf) {
  __shared__ float qs[1024];   // [b][i] for this head
  __shared__ float sred[2048]; // [ig][b][jl]
  const int tid = threadIdx.x;
  const int h = blockIdx.x >> 5, jb = blockIdx.x & 31;
  {
    int b = tid >> 5, i4 = tid & 31;
    ((float4*)qs)[b * 32 + i4] = ((const float4*)Qp)[b * 256 + (h << 5) + i4];
  }
  __syncthreads();
  const int jl = tid & 31, ig = tid >> 5;
  const float* wkp = Wk + (size_t)((h << 7) + (ig << 4)) * DD + (jb << 5) + jl;
  float acc[8];
#pragma unroll
  for (int b = 0; b < 8; ++b) acc[b] = 0.f;
#pragma unroll
  for (int ii = 0; ii < 16; ++ii) {
    float wv = wkp[(size_t)ii * DD];
    int i = (ig << 4) + ii;
#pragma unroll
    for (int b = 0; b < 8; ++b) acc[b] = fmaf(qs[(b << 7) + i], wv, acc[b]);
  }
#pragma unroll
  for (int b = 0; b < 8; ++b) sred[ig * 256 + (b << 5) + jl] = acc[b];
  __syncthreads();
  {
    int b = tid >> 5, j2 = tid & 31;
    float s = 0.f;
#pragma unroll
    for (int g = 0; g < 8; ++g) s += sred[g * 256 + (b << 5) + j2];
    wbuf[(size_t)((b << 3) + h) * DD + (jb << 5) + j2] = s;
  }
}

// ---------- logits + xf store: grid 8192 = b(8) x tile(64) x chunk(16), 512 thr ----------
// 64 ch per chunk; LDS = 32 KB union (staging 16x101 f4 / reduce 8192 f / transpose 64x17 f4)
__global__ __launch_bounds__(512, 4) void k_logits(
    const float* __restrict__ inp, const float* __restrict__ convb,
    const float* __restrict__ cwT, const float* __restrict__ wbuf,
    const unsigned long long* __restrict__ argbest,
    float* __restrict__ plog, float* __restrict__ xf) {
  __shared__ float4 sred4[2048];   // 32 KB
  const int tid = threadIdx.x, bx = blockIdx.x;
  const int b = bx >> 10, tile = (bx >> 4) & 63, cidx = bx & 15;
  const int R0 = (tile >> 3) << 3, C0 = (tile & 7) << 3;
  const unsigned idxq = 0xFFFFFFFFu - (unsigned)(argbest[b] & 0xFFFFFFFFull);
  const float* inpb = inp + (size_t)b * NTOK * DD;
  const float* qrow = inpb + (size_t)idxq * DD;
  const int gg = tid & 15, ts = tid >> 4;                      // staging roles
  const int jg = tid >> 5, rq = (tid >> 3) & 3, ca = tid & 7;  // conv roles
  const int r0a = rq << 1;
  const int jc = cidx << 6;

  float acc[2][8];
#pragma unroll
  for (int i = 0; i < 2; ++i)
#pragma unroll
    for (int h = 0; h < 8; ++h) acc[i][h] = 0.f;
  float4 xs0, xs1;   // conv features kept for xf store

  {  // stage 64 channels of the 10x10 halo (relu(x - q))
    const int js = jc + (gg << 2);
    float4 qv = *(const float4*)(qrow + js);
    for (int t = ts; t < 100; t += 32) {
      int tr = t / 10, tc = t - tr * 10;
      int gr = R0 - 1 + tr, gc = C0 - 1 + tc;
      float4 v = make_float4(0.f, 0.f, 0.f, 0.f);
      if (gr >= 0 && gr < 64 && gc >= 0 && gc < 64) {
        float4 rv = *(const float4*)(inpb + (size_t)((gr << 6) + gc) * DD + js);
        v.x = fmaxf(rv.x - qv.x, 0.f); v.y = fmaxf(rv.y - qv.y, 0.f);
        v.z = fmaxf(rv.z - qv.z, 0.f); v.w = fmaxf(rv.w - qv.w, 0.f);
      }
      sred4[gg * LSTRIDE + t] = v;
    }
  }
  __syncthreads();
  {
    const int j4 = jc + (jg << 2);
    float4 cwr[9];
#pragma unroll
    for (int p = 0; p < 9; ++p) cwr[p] = *(const float4*)(cwT + p * DD + j4);
    float4 cb4 = *(const float4*)(convb + j4);
    const float4* fb = sred4 + jg * LSTRIDE;
    float4 x0 = cb4, x1 = cb4;
    {
      float4 rw[4][3];
#pragma unroll
      for (int rr = 0; rr < 4; ++rr)
#pragma unroll
        for (int dc = 0; dc < 3; ++dc)
          rw[rr][dc] = fb[(r0a + rr) * 10 + ca + dc];
#pragma unroll
      for (int dr = 0; dr < 3; ++dr)
#pragma unroll
        for (int dc = 0; dc < 3; ++dc) {
          float4 w = cwr[dr * 3 + dc];
          float4 f0 = rw[dr][dc], f1 = rw[dr + 1][dc];
          x0.x = fmaf(w.x, f0.x, x0.x); x0.y = fmaf(w.y, f0.y, x0.y);
          x0.z = fmaf(w.z, f0.z, x0.z); x0.w = fmaf(w.w, f0.w, x0.w);
          x1.x = fmaf(w.x, f1.x, x1.x); x1.y = fmaf(w.y, f1.y, x1.y);
          x1.z = fmaf(w.z, f1.z, x1.z); x1.w = fmaf(w.w, f1.w, x1.w);
        }
      x0.x += rw[1][1].x; x0.y += rw[1][1].y; x0.z += rw[1][1].z; x0.w += rw[1][1].w;
      x1.x += rw[2][1].x; x1.y += rw[2][1].y; x1.z += rw[2][1].z; x1.w += rw[2][1].w;
    }
    xs0 = x0; xs1 = x1;
#pragma unroll
    for (int h = 0; h < 8; ++h) {
      float4 whv = *(const float4*)(wbuf + (size_t)(b * 8 + h) * DD + j4);
      float a0 = acc[0][h], a1 = acc[1][h];
      a0 = fmaf(whv.x, x0.x, a0); a0 = fmaf(whv.y, x0.y, a0);
      a0 = fmaf(whv.z, x0.z, a0); a0 = fmaf(whv.w, x0.w, a0);
      a1 = fmaf(whv.x, x1.x, a1); a1 = fmaf(whv.y, x1.y, a1);
      a1 = fmaf(whv.z, x1.z, a1); a1 = fmaf(whv.w, x1.w, a1);
      acc[0][h] = a0; acc[1][h] = a1;
    }
  }
  // ---- reduce over 16 ch-groups -> per-chunk partial logits ----
  __syncthreads();
  float* red = (float*)sred4;
#pragma unroll
  for (int it = 0; it < 2; ++it)
#pragma unroll
    for (int h = 0; h < 8; ++h)
      red[jg * 512 + ((r0a + it) * 8 + ca) * 8 + h] = acc[it][h];
  __syncthreads();
  {
    float s = 0.f;
#pragma unroll
    for (int g = 0; g < 16; ++g) s += red[g * 512 + tid];
    plog[(size_t)bx * 512 + tid] = s;
  }
  // ---- xf store: transpose regs -> LDS -> coalesced global ----
  __syncthreads();   // all red reads complete before overwrite
  float4* ldsx = sred4;  // [64 tok][17 float4] (pad 1)
  {
    const int tk0 = (r0a << 3) + ca;
    ldsx[tk0 * 17 + jg] = xs0;
    ldsx[(tk0 + 8) * 17 + jg] = xs1;
  }
  __syncthreads();
  {
    float* xfb = xf + (size_t)((b << 6) + tile) * (64 * DD) + jc;
#pragma unroll
    for (int it = 0; it < 2; ++it) {
      int idx = (it << 9) + tid;       // 0..1023
      int tk = idx >> 4, q = idx & 15;
      float4 v = ldsx[tk * 17 + q];
      *(float4*)(xfb + (size_t)tk * DD + (q << 2)) = v;
    }
  }
}

// ---------- y pass (softmax fused): grid 512 = b x tile, 512 thr ----------
__global__ __launch_bounds__(512, 8) void k_ysum(
    const float* __restrict__ plog, const float* __restrict__ xf,
    float2* __restrict__ msbuf, float* __restrict__ ypart) {
  __shared__ float atile[512];
  const int tid = threadIdx.x, bt = blockIdx.x;
  // ---- sum 16 chunk-partials; logit at [tok*8+h] ----
  {
    const float* pp = plog + (size_t)bt * 16 * 512;
    float s = 0.f;
#pragma unroll
    for (int c = 0; c < 16; ++c) s += pp[c * 512 + tid];
    atile[tid] = s * 0.03125f;
  }
  __syncthreads();
  // ---- per-head softmax: wave w = head, lane l = token ----
  {
    const int w = tid >> 6, l = tid & 63;
    float v = atile[l * 8 + w];
    float mx = v;
#pragma unroll
    for (int mk = 32; mk >= 1; mk >>= 1) mx = fmaxf(mx, __shfl_xor(mx, mk));
    float e = __expf(v - mx);
    float Ss = e;
#pragma unroll
    for (int mk = 32; mk >= 1; mk >>= 1) Ss += __shfl_xor(Ss, mk);
    __syncthreads();   // all reads of atile done before overwrite
    atile[l * 8 + w] = e;
    if (l == 0) {
      int b = bt >> 6, tile = bt & 63;
      msbuf[((b << 3) + w) * 64 + tile] = make_float2(mx, Ss);
    }
  }
  __syncthreads();
  // ---- streaming weighted sum over xf ----
  const float* xbase = xf + (size_t)bt * (64 * DD) + (tid << 1);
  float2 acc[8];
#pragma unroll
  for (int h = 0; h < 8; ++h) acc[h] = make_float2(0.f, 0.f);
#pragma unroll 4
  for (int t = 0; t < 64; ++t) {
    float2 v = *(const float2*)(xbase + (size_t)t * DD);
    float4 aA = *(const float4*)&atile[t * 8];
    float4 aB = *(const float4*)&atile[t * 8 + 4];
    acc[0].x = fmaf(aA.x, v.x, acc[0].x); acc[0].y = fmaf(aA.x, v.y, acc[0].y);
    acc[1].x = fmaf(aA.y, v.x, acc[1].x); acc[1].y = fmaf(aA.y, v.y, acc[1].y);
    acc[2].x = fmaf(aA.z, v.x, acc[2].x); acc[2].y = fmaf(aA.z, v.y, acc[2].y);
    acc[3].x = fmaf(aA.w, v.x, acc[3].x); acc[3].y = fmaf(aA.w, v.y, acc[3].y);
    acc[4].x = fmaf(aB.x, v.x, acc[4].x); acc[4].y = fmaf(aB.x, v.y, acc[4].y);
    acc[5].x = fmaf(aB.y, v.x, acc[5].x); acc[5].y = fmaf(aB.y, v.y, acc[5].y);
    acc[6].x = fmaf(aB.z, v.x, acc[6].x); acc[6].y = fmaf(aB.z, v.y, acc[6].y);
    acc[7].x = fmaf(aB.w, v.x, acc[7].x); acc[7].y = fmaf(aB.w, v.y, acc[7].y);
  }
  const int b = bt >> 6, tile = bt & 63;
#pragma unroll
  for (int h = 0; h < 8; ++h)
    *(float2*)(ypart + ((size_t)((b * 8 + h) * 64 + tile)) * DD + (tid << 1)) = acc[h];
}

// ---------- flash-combine (512 blocks: bh x 8 ch-splits); computes l0 inline ----------
__global__ void k_comb(const float2* __restrict__ msbuf, const float* __restrict__ wbuf,
                       const float* __restrict__ cls, const float* __restrict__ ypart,
                       float* __restrict__ ybuf) {
  __shared__ float redl[256];
  __shared__ float wgt[64];
  __shared__ float wclss;
  __shared__ float4 sacc[256];
  int tid = threadIdx.x;
  int bh = blockIdx.x >> 3, cs = blockIdx.x & 7;
  {  // l0 = (w . cls) * scale   (qh·bk_h dropped: softmax-invariant)
    float4 a = ((const float4*)(wbuf + (size_t)bh * DD))[tid];
    float4 c = ((const float4*)cls)[tid];
    redl[tid] = a.x * c.x + a.y * c.y + a.z * c.z + a.w * c.w;
  }
  __syncthreads();
  for (int s = 128; s > 0; s >>= 1) { if (tid < s) redl[tid] += redl[tid + s]; __syncthreads(); }
  float l0 = redl[0] * 0.03125f;
  if (tid < 64) {
    float2 ms = msbuf[bh * 64 + tid];
    float m = ms.x, S = ms.y;
    float M = m;
#pragma unroll
    for (int mk = 32; mk >= 1; mk >>= 1) M = fmaxf(M, __shfl_xor(M, mk));
    M = fmaxf(M, l0);
    float w = __expf(m - M);
    float z = S * w;
#pragma unroll
    for (int mk = 32; mk >= 1; mk >>= 1) z += __shfl_xor(z, mk);
    float ec = __expf(l0 - M);
    float Z = z + ec;
    wgt[tid] = w / Z;
    if (tid == 0) wclss = ec / Z;
  }
  __syncthreads();
  int ch4 = (cs << 5) + (tid & 31);
  int tg = tid >> 5;
  const float* yp = ypart + (size_t)bh * 64 * DD + (ch4 << 2);
  float4 acc = make_float4(0.f, 0.f, 0.f, 0.f);
#pragma unroll
  for (int tt = 0; tt < 8; ++tt) {
    int t = tg * 8 + tt;
    float w = wgt[t];
    float4 v = *(const float4*)(yp + (size_t)t * DD);
    acc.x = fmaf(w, v.x, acc.x); acc.y = fmaf(w, v.y, acc.y);
    acc.z = fmaf(w, v.z, acc.z); acc.w = fmaf(w, v.w, acc.w);
  }
  sacc[tg * 32 + (tid & 31)] = acc;
  __syncthreads();
  if (tid < 32) {
    int c4 = (cs << 5) + tid;
    float4 s = sacc[tid];
#pragma unroll
    for (int g = 1; g < 8; ++g) {
      float4 v = sacc[g * 32 + tid];
      s.x += v.x; s.y += v.y; s.z += v.z; s.w += v.w;
    }
    float wc = wclss;
    float4 cv = *(const float4*)(cls + (c4 << 2));
    s.x = fmaf(wc, cv.x, s.x); s.y = fmaf(wc, cv.y, s.y);
    s.z = fmaf(wc, cv.z, s.z); s.w = fmaf(wc, cv.w, s.w);
    *(float4*)(ybuf + (size_t)bh * DD + (c4 << 2)) = s;
  }
}

__global__ void k_o1(const float* __restrict__ Wv, const float* __restrict__ bv,
                     const float* __restrict__ Qp, const float* __restrict__ ybuf,
                     float* __restrict__ O1) {
  int wave = threadIdx.x >> 6, lane = threadIdx.x & 63;
  int b = blockIdx.x >> 8;
  int i = ((blockIdx.x & 255) << 2) + wave;
  int h = i >> 7;
  const float4* wr = (const float4*)(Wv + (size_t)i * DD);
  const float4* yr = (const float4*)(ybuf + (size_t)(b * 8 + h) * DD);
  float s = 0.f;
#pragma unroll
  for (int k = 0; k < 4; ++k) {
    float4 a = wr[lane + (k << 6)], x = yr[lane + (k << 6)];
    s = fmaf(a.x, x.x, s); s = fmaf(a.y, x.y, s);
    s = fmaf(a.z, x.z, s); s = fmaf(a.w, x.w, s);
  }
  for (int m = 32; m > 0; m >>= 1) s += __shfl_xor(s, m);
  if (lane == 0) O1[b * DD + i] = Qp[b * DD + i] + bv[i] + s;
}

__global__ void k_o2(const float* __restrict__ Wo, const float* __restrict__ bo,
                     const float* __restrict__ O1, float* __restrict__ O2) {
  int wave = threadIdx.x >> 6, lane = threadIdx.x & 63;
  int b = blockIdx.x >> 8;
  int i = ((blockIdx.x & 255) << 2) + wave;
  const float4* wr = (const float4*)(Wo + (size_t)i * DD);
  const float4* xr = (const float4*)(O1 + (size_t)b * DD);
  float s = 0.f;
#pragma unroll
  for (int k = 0; k < 4; ++k) {
    float4 a = wr[lane + (k << 6)], x = xr[lane + (k << 6)];
    s = fmaf(a.x, x.x, s); s = fmaf(a.y, x.y, s);
    s = fmaf(a.z, x.z, s); s = fmaf(a.w, x.w, s);
  }
  for (int m = 32; m > 0; m >>= 1) s += __shfl_xor(s, m);
  if (lane == 0) O2[b * DD + i] = O1[b * DD + i] + fmaxf(s + bo[i], 0.f);
}

__global__ void k_out(const float* __restrict__ Wfc, const float* __restrict__ bfc,
                      const float* __restrict__ O2, float* __restrict__ out) {
  int wave = threadIdx.x >> 6, lane = threadIdx.x & 63;
  for (int p = wave; p < 16; p += 4) {
    int b = p >> 1, cc = p & 1;
    const float4* o = (const float4*)(O2 + (size_t)b * DD);
    const float4* wr = (const float4*)(Wfc + (size_t)cc * DD);
    float s = 0.f;
#pragma unroll
    for (int k = 0; k < 4; ++k) {
      float4 a = o[lane + (k << 6)], x = wr[lane + (k << 6)];
      s = fmaf(a.x, x.x, s); s = fmaf(a.y, x.y, s);
      s = fmaf(a.z, x.z, s); s = fmaf(a.w, x.w, s);
    }
    for (int m = 32; m > 0; m >>= 1) s += __shfl_xor(s, m);
    if (lane == 0) out[p] = s + bfc[cc];
  }
}

extern "C" void kernel_launch(void* const* d_in, const int* in_sizes, int n_in,
                              void* d_out, int out_size, void* d_ws, size_t ws_size,
                              hipStream_t stream) {
  const float* inp   = (const float*)d_in[0];
  const float* Wenc  = (const float*)d_in[1];
  const float* benc  = (const float*)d_in[2];
  const float* cls   = (const float*)d_in[3];
  const float* convw = (const float*)d_in[4];
  const float* convb = (const float*)d_in[5];
  const float* Wq    = (const float*)d_in[6];
  const float* bq    = (const float*)d_in[7];
  const float* Wk    = (const float*)d_in[8];
  const float* bv    = (const float*)d_in[11];
  const float* Wv    = (const float*)d_in[10];
  const float* Wo    = (const float*)d_in[12];
  const float* bo    = (const float*)d_in[13];
  const float* Wfc   = (const float*)d_in[14];
  const float* bfc   = (const float*)d_in[15];
  float* out = (float*)d_out;
  float* W = (float*)d_ws;
  unsigned long long* argbest = (unsigned long long*)(W + FO_ARG);
  float* cwT   = W + FO_CWT;
  float* Qp    = W + FO_QP;
  float* wbuf  = W + FO_W;
  float2* msbuf = (float2*)(W + FO_MS);
  float* ypart = W + FO_YP;
  float* plog  = W + FO_PL;
  float* xf    = W + FO_XF;
  float* ybuf  = W + FO_Y;
  float* O1    = W + FO_O1;
  float* O2    = W + FO_O2;

  hipLaunchKernelGGL(k_init,    dim3(36),   dim3(256), 0, stream, convw, cwT, argbest);
  hipLaunchKernelGGL(k_argmax1, dim3(2048), dim3(256), 0, stream, inp, Wenc, benc, argbest);
  hipLaunchKernelGGL(k_qp,      dim3(2048), dim3(256), 0, stream, inp, Wq, bq, argbest, Qp);
  hipLaunchKernelGGL(k_w,       dim3(256),  dim3(256), 0, stream, Wk, Qp, wbuf);
  hipLaunchKernelGGL(k_logits,  dim3(8192), dim3(512), 0, stream, inp, convb, cwT, wbuf, argbest, plog, xf);
  hipLaunchKernelGGL(k_ysum,    dim3(512),  dim3(512), 0, stream, plog, xf, msbuf, ypart);
  hipLaunchKernelGGL(k_comb,    dim3(512),  dim3(256), 0, stream, msbuf, wbuf, cls, ypart, ybuf);
  hipLaunchKernelGGL(k_o1,      dim3(2048), dim3(256), 0, stream, Wv, bv, Qp, ybuf, O1);
  hipLaunchKernelGGL(k_o2,      dim3(2048), dim3(256), 0, stream, Wo, bo, O1, O2);
  hipLaunchKernelGGL(k_out,     dim3(1),    dim3(256), 0, stream, Wfc, bfc, O2, out);
}